// Round 1
// 280.940 us; speedup vs baseline: 1.0023x; 1.0023x over previous
//
#include <hip/hip_runtime.h>

#define BB 1024
#define VV 50000
#define TT 50

// ---------------- Phase 1: streaming exp-sum ----------------
// Row = 12500 float4. Split into 4 segments of 3125 float4.
// Grid = BB*4 blocks of 256 threads; each thread: 12 full float4 + remainder.
#define SEGS    4
#define SEG4    3125                      // float4 per segment
#define P1_NTH  256
#define P1_FULL 12                        // 12*256 = 3072
#define P1_REM  (SEG4 - P1_FULL * P1_NTH) // 53

__global__ __launch_bounds__(P1_NTH) void rowsum_exp_kernel(
    const float* __restrict__ output,
    float*       __restrict__ partials)
{
    const int bid = blockIdx.x;
    const int r   = bid >> 2;     // / SEGS
    const int seg = bid & 3;      // % SEGS
    const int tid = threadIdx.x;

    const float4* __restrict__ p =
        (const float4*)(output + (size_t)r * VV) + seg * SEG4;

    // back-to-back loads: maximize outstanding VMEM before any VALU use
    float4 v[P1_FULL];
    #pragma unroll
    for (int u = 0; u < P1_FULL; ++u) v[u] = p[tid + P1_NTH * u];
    const bool has_rem = tid < P1_REM;
    float4 vt = make_float4(0.f, 0.f, 0.f, 0.f);
    if (has_rem) vt = p[tid + P1_NTH * P1_FULL];

    float s0 = 0.f, s1 = 0.f, s2 = 0.f, s3 = 0.f;
    #pragma unroll
    for (int u = 0; u < P1_FULL; ++u) {
        s0 += __expf(v[u].x);
        s1 += __expf(v[u].y);
        s2 += __expf(v[u].z);
        s3 += __expf(v[u].w);
    }
    if (has_rem) {
        s0 += __expf(vt.x);
        s1 += __expf(vt.y);
        s2 += __expf(vt.z);
        s3 += __expf(vt.w);
    }
    float sum = (s0 + s1) + (s2 + s3);

    #pragma unroll
    for (int off = 32; off > 0; off >>= 1)
        sum += __shfl_down(sum, off, 64);

    __shared__ float wsum[4];
    const int lane = tid & 63;
    const int wave = tid >> 6;
    if (lane == 0) wsum[wave] = sum;
    __syncthreads();
    if (tid == 0)
        partials[bid] = (wsum[0] + wsum[1]) + (wsum[2] + wsum[3]);
}

// ---------------- Phase 2: wave-per-row tail math ----------------
// One 64-lane wave per row; 4 rows per 256-thread block; grid = BB/4.
#define P2_NTH 256

__global__ __launch_bounds__(P2_NTH) void tail_kernel(
    const float* __restrict__ output,
    const int*   __restrict__ target,
    const int*   __restrict__ tails,
    const int*   __restrict__ tail_len,
    const float* __restrict__ partials,
    float*       __restrict__ out)
{
    const int wave = threadIdx.x >> 6;
    const int lane = threadIdx.x & 63;
    const int r    = blockIdx.x * 4 + wave;   // grid = BB/4 -> r < BB

    const float* __restrict__ row = output + (size_t)r * VV;
    const int L = tail_len[r];

    // total = sum of 4 segment partials, broadcast to all lanes
    float tot = (lane < SEGS) ? partials[r * SEGS + lane] : 0.f;
    #pragma unroll
    for (int off = 32; off > 0; off >>= 1)
        tot += __shfl_xor(tot, off, 64);

    const float ts     = row[target[r]];
    const float log_pl = ts - __logf(tot);

    // parallel tail gather: lane j handles tail element j
    float sv = 0.f, ev = 0.f;
    if (lane < L) {                 // L <= TT = 50 < 64
        sv = row[tails[r * TT + lane]];
        ev = __expf(sv);
    }

    // above = sum sv, sum_es = sum ev (butterfly, all lanes get result)
    float a = sv, e = ev;
    #pragma unroll
    for (int off = 32; off > 0; off >>= 1) {
        a += __shfl_xor(a, off, 64);
        e += __shfl_xor(e, off, 64);
    }
    const float others = tot - __expf(ts) - e;

    // inclusive suffix scan of ev: run_j = es_j + ... + es_{L-1}
    float run = ev;
    #pragma unroll
    for (int off = 1; off < 64; off <<= 1) {
        float o = __shfl_down(run, off, 64);
        if (lane + off < 64) run += o;
    }

    // all 50 logs evaluate in parallel (vs serial chain on thread 0)
    float bl = (lane < L) ? __logf(run + others) : 0.f;
    #pragma unroll
    for (int off = 32; off > 0; off >>= 1)
        bl += __shfl_xor(bl, off, 64);

    if (lane == 0) {
        const float tail_term = (L > 0) ? (a - bl) : 0.f;
        out[r] = -(log_pl + tail_term);
    }
}

extern "C" void kernel_launch(void* const* d_in, const int* in_sizes, int n_in,
                              void* d_out, int out_size, void* d_ws, size_t ws_size,
                              hipStream_t stream) {
    const float* output   = (const float*)d_in[0];
    const int*   target   = (const int*)d_in[1];
    const int*   tails    = (const int*)d_in[2];
    const int*   tail_len = (const int*)d_in[3];
    float*       out      = (float*)d_out;
    float*       partials = (float*)d_ws;   // BB*SEGS floats = 16 KB

    rowsum_exp_kernel<<<BB * SEGS, P1_NTH, 0, stream>>>(output, partials);
    tail_kernel<<<BB / 4, P2_NTH, 0, stream>>>(output, target, tails, tail_len,
                                               partials, out);
}